// Round 9
// baseline (3218.122 us; speedup 1.0000x reference)
//
#include <hip/hip_runtime.h>
#include <cstdint>
#include <cstddef>

// Problem constants
#define BB   64     // batch
#define TT   512    // time steps
#define HH   256    // hidden
#define G4   1024   // 4*H
#define NL   8      // layers
#define NW   32     // workgroups per layer (hidden-unit slices)
#define HPW  8      // hidden units per WG
#define NR   32     // gate rows per WG (4 gates * HPW)

// Watchdog: poll breaks after this many iterations and proceeds (bounded
// wrong-answer instead of GPU hang). Never triggers when protocol is sound.
#define POLL_BOUND (1 << 15)

typedef _Float16 half8 __attribute__((ext_vector_type(8)));
typedef float   floatx4 __attribute__((ext_vector_type(4)));

__device__ __forceinline__ float sigm(float v)   { return 1.0f / (1.0f + __expf(-v)); }
__device__ __forceinline__ float tanh_f(float v) { return 1.0f - 2.0f / (__expf(2.0f * v) + 1.0f); }

// ---- coherence helpers (ONLY the proven system-scope primitives) ----------
// Producer: data stores sc0sc1 -> s_waitcnt vmcnt(0) -> flag store sc0sc1.
// Consumer: poll flag sc0sc1; then PLAIN cached loads of the data (each data
// address is written exactly once per launch and only read after the flag:
// first-touch L2 fill pulls post-store bytes from IF$). Proven at 1908us and
// in the R5/R6/R7 passes.
// R7 lesson (counters): 2B sc0sc1 stores cause ~2x write amplification
// (WRITE_SIZE 266MB vs 160MB expected) + slow partial-sector acks at the
// coherence point -> publish ONLY in 16B units.
__device__ __forceinline__ void gstore8_x(_Float16* p, half8 d) {
  asm volatile("global_store_dwordx4 %0, %1, off sc0 sc1" :: "v"(p), "v"(d) : "memory");
}
__device__ __forceinline__ void stdword_x(int* p, int v) {
  asm volatile("global_store_dword %0, %1, off sc0 sc1" :: "v"(p), "v"(v) : "memory");
}
__device__ __forceinline__ void wait_vm0() {
  asm volatile("s_waitcnt vmcnt(0)" ::: "memory");
}
__device__ __forceinline__ int ldflag_x(const int* p) {
  int v; asm volatile("global_load_dword %0, %1, off sc0 sc1" : "=v"(v) : "v"(p) : "memory");
  wait_vm0(); return v;
}

// hseq layout per layer: [t][kblk=H/8=32][b=64][8] fp16 (MFMA A-fragment friendly)
#define TSTRIDE ((size_t)32 * BB * 8)         // 16384 elems per t
#define LSTRIDE ((size_t)TT * TSTRIDE)        // 8,388,608 elems per layer (16 MB)

// ---------------------------------------------------------------------------
// xg0 table: table[v][n] = sum_e emb[v][e] * Wih0[n][e]   (biases NOT included)
__global__ void build_xg0(const float* __restrict__ emb, const float* __restrict__ Wih0,
                          float* __restrict__ table) {
  int i = blockIdx.x * 256 + threadIdx.x;
  if (i >= 23 * G4) return;
  int v = i >> 10, n = i & (G4 - 1);
  float a = 0.f;
#pragma unroll
  for (int e = 0; e < 16; ++e) a += emb[v * 16 + e] * Wih0[n * 16 + e];
  table[i] = a;
}

// ---------------------------------------------------------------------------
// Persistent pipelined LSTM -- proven geometry (8 layers x 32 slices x 256
// thr, LDS weights, sc0sc1 exchange), ONE barrier per step:
//  (J)  in-register gates via two shfl_xor(8)  [verified correct in R7]
//  (P16) per-wave publish: cell lanes stage h into a WAVE-PRIVATE 256B LDS
//       tile (2B writes), wave-local lgkmcnt(0) (same-wave LDS is in-order,
//       no __syncthreads), then lanes 0..15 re-read half8 and issue ONE
//       coalesced 16B sc0sc1 store each -- identical segment pattern to the
//       proven baseline publish, drained by 4 waves in parallel.
//  (F)  flag aggregation: per-wave vmcnt(0) ack -> LDS atomicAdd; the 4th
//       wave of step t releases the slice flag  [verified correct in R7].
__global__ __launch_bounds__(256, 1) void lstm_pipeline(
    const int*   __restrict__ x,         // [B][T]
    const float* __restrict__ Wih_rest,  // [7][1024][256]
    const float* __restrict__ Whh,       // [8][1024][256]
    const float* __restrict__ bih,       // [8][1024]
    const float* __restrict__ bhh,       // [8][1024]
    const float* __restrict__ xg0t,      // [23][1024]
    _Float16* __restrict__ hseq,         // NL * LSTRIDE fp16
    int* __restrict__ cnt)               // [NL][NW] step counters (IF$)
{
  const int l   = blockIdx.x & 7;
  const int w   = blockIdx.x >> 3;
  const int tid = threadIdx.x;
  const int lane = tid & 63;
  const int p    = tid >> 6;        // wave index = M-tile index (batch/16)

  __shared__ __align__(16) _Float16 wlds[64 * NR * 8]; // [kc 0..63][n 0..31][8]
  __shared__ __align__(16) _Float16 hl[4][16][8];      // wave-private h staging
  __shared__ float  blds[NR];
  __shared__ float  tlds[23 * NR];
  __shared__ int    pubcnt;

  // ---- one-time init: gather this WG's 32 gate rows into LDS as fp16 ----
  // wlds n-rows: 0..7 = gate i (units 0..7), 8..15 = f, 16..23 = g, 24..31 = o
  for (int idx = tid; idx < 64 * NR; idx += 256) {
    int kc = idx >> 5;          // 0..31 input half, 32..63 recurrent half
    int n  = idx & 31;
    int g = n >> 3, jl = n & 7;
    int gr = g * 256 + w * HPW + jl;
    float v[8];
    if (kc < 32) {
      if (l == 0) { for (int j = 0; j < 8; ++j) v[j] = 0.f; }
      else {
        const float* src = Wih_rest + ((size_t)(l - 1) * G4 + gr) * HH + kc * 8;
        for (int j = 0; j < 8; ++j) v[j] = src[j];
      }
    } else {
      const float* src = Whh + ((size_t)l * G4 + gr) * HH + (kc - 32) * 8;
      for (int j = 0; j < 8; ++j) v[j] = src[j];
    }
    _Float16* dst = wlds + (size_t)idx * 8;
    for (int j = 0; j < 8; ++j) dst[j] = (_Float16)v[j];
  }
  if (tid < NR) {
    int g = tid >> 3, jl = tid & 7;
    int gr = g * 256 + w * HPW + jl;
    blds[tid] = bih[l * G4 + gr] + bhh[l * G4 + gr];
  }
  if (l == 0) {
    for (int idx = tid; idx < 23 * NR; idx += 256) {
      int v = idx >> 5, n = idx & 31;
      int g = n >> 3, jl = n & 7;
      tlds[idx] = xg0t[v * G4 + g * 256 + w * HPW + jl];
    }
  }
  if (tid == 0) pubcnt = 0;
  // agent-scope acquire: invalidate stale L1/L2 lines before cached h reads
  if (tid == 0) (void)__hip_atomic_load(cnt, __ATOMIC_ACQUIRE, __HIP_MEMORY_SCOPE_AGENT);
  __syncthreads();

  const int arow = p * 16 + (lane & 15);  // A-fragment batch row
  const int kq   = lane >> 4;             // quarter-wave -> k chunk within tile
  const int n0   = lane & 15;             // B-fragment col (tile 0)
  const int n1   = 16 + n0;               // B-fragment col (tile 1)
  const int cu   = lane & 7;              // cell: unit within slice
  const bool cellane = (n0 < 8);          // lanes that own a unit's cell
  const int rowb = p * 16 + kq * 4;       // cell: first of this lane's 4 batch rows

  const _Float16* hin  = hseq + (size_t)(l > 0 ? l - 1 : 0) * LSTRIDE;
  _Float16*       hrec = hseq + (size_t)l * LSTRIDE;

  float bi = 0.f, bf = 0.f, bg = 0.f, bo = 0.f;
  if (cellane) { bi = blds[cu]; bf = blds[8 + cu]; bg = blds[16 + cu]; bo = blds[24 + cu]; }

  float cst[4] = {0.f, 0.f, 0.f, 0.f};    // c-state: batch rowb+r, unit w*8+cu

  for (int t = 0; t < TT; ++t) {
    // ---- parallel polls: wave3 = own layer step t-1, wave2 = layer below ----
    if (t > 0 && p == 3) {
      const int* f = cnt + l * NW;
      for (int it = 0; it < POLL_BOUND; ++it) {
        int v = ldflag_x(f + (lane & 31));
        if (__all(v >= t)) break;
        __builtin_amdgcn_s_sleep(1);
      }
    }
    if (l > 0 && p == 2) {
      const int* f = cnt + (l - 1) * NW;
      for (int it = 0; it < POLL_BOUND; ++it) {
        int v = ldflag_x(f + (lane & 31));
        if (__all(v >= t + 1)) break;
        __builtin_amdgcn_s_sleep(1);
      }
    }
    __syncthreads();   // barrier A -- the ONLY barrier in the step

    // ---- issue ALL loads (input half + recurrent half), plain cached ----
    half8 aA[8], aB[8];
    if (l > 0) {
      const _Float16* ain = hin + (size_t)t * TSTRIDE;
#pragma unroll
      for (int kt = 0; kt < 8; ++kt) {
        int kc = kt * 4 + kq;
        aA[kt] = *(const half8*)(ain + ((size_t)(kc * 64 + arow) << 3));
      }
    }
    if (t > 0) {
      const _Float16* ain = hrec + (size_t)(t - 1) * TSTRIDE;
#pragma unroll
      for (int kt = 0; kt < 8; ++kt) {
        int kc = kt * 4 + kq;
        aB[kt] = *(const half8*)(ain + ((size_t)(kc * 64 + arow) << 3));
      }
    }

    floatx4 acc0 = {0.f, 0.f, 0.f, 0.f};   // tile0: cols = {i x8, f x8}
    floatx4 acc1 = {0.f, 0.f, 0.f, 0.f};   // tile1: cols = {g x8, o x8}
    if (l > 0) {
#pragma unroll
      for (int kt = 0; kt < 8; ++kt) {
        int kc = kt * 4 + kq;
        half8 w0 = *(const half8*)(wlds + ((kc * 32 + n0) << 3));
        half8 w1 = *(const half8*)(wlds + ((kc * 32 + n1) << 3));
        acc0 = __builtin_amdgcn_mfma_f32_16x16x32_f16(aA[kt], w0, acc0, 0, 0, 0);
        acc1 = __builtin_amdgcn_mfma_f32_16x16x32_f16(aA[kt], w1, acc1, 0, 0, 0);
      }
    }
    if (t > 0) {
#pragma unroll
      for (int kt = 0; kt < 8; ++kt) {
        int kc = kt * 4 + kq;
        half8 w0 = *(const half8*)(wlds + (((32 + kc) * 32 + n0) << 3));
        half8 w1 = *(const half8*)(wlds + (((32 + kc) * 32 + n1) << 3));
        acc0 = __builtin_amdgcn_mfma_f32_16x16x32_f16(aB[kt], w0, acc0, 0, 0, 0);
        acc1 = __builtin_amdgcn_mfma_f32_16x16x32_f16(aB[kt], w1, acc1, 0, 0, 0);
      }
    }

    // ---- (J) gate exchange: lane c<8 holds i,g of unit c; partner c+8 holds
    //      f,o of the same unit. Two shfl_xor(8) complete the set. C layout:
    //      col = lane&15, row = kq*4 + r (+ p*16). ----
    float xf[4], xo[4];
#pragma unroll
    for (int r = 0; r < 4; ++r) {
      xf[r] = __shfl_xor(acc0[r], 8);
      xo[r] = __shfl_xor(acc1[r], 8);
    }

    // ---- cell in-register -> wave-private LDS staging (2B writes) ----
    if (cellane) {
#pragma unroll
      for (int r = 0; r < 4; ++r) {
        float gi = acc0[r] + bi;
        float gf = xf[r]   + bf;
        float gg = acc1[r] + bg;
        float go = xo[r]   + bo;
        if (l == 0) {
          const int xv = x[(rowb + r) * TT + t];
          const float* tb = tlds + xv * NR;
          gi += tb[cu]; gf += tb[8 + cu]; gg += tb[16 + cu]; go += tb[24 + cu];
        }
        const float iv = sigm(gi), fv = sigm(gf), gv = tanh_f(gg), ov = sigm(go);
        cst[r] = fv * cst[r] + iv * gv;
        const float hv = ov * tanh_f(cst[r]);
        hl[p][kq * 4 + r][cu] = (_Float16)hv;
      }
    }
    // wave-local LDS ordering: same-wave DS ops are in-order; the waitcnt +
    // memory clobber stop the compiler lifting the reads above the writes.
    asm volatile("s_waitcnt lgkmcnt(0)" ::: "memory");
    __builtin_amdgcn_sched_barrier(0);

    // ---- (P16) per-wave 16B publish: lane j<16 stores batch row p*16+j ----
    if (lane < 16) {
      half8 hv8 = *(const half8*)&hl[p][lane][0];
      gstore8_x(hrec + (size_t)t * TSTRIDE + ((size_t)(w * 64 + p * 16 + lane) << 3), hv8);
    }

    // ---- (F) per-wave ack, then LDS-aggregated flag release ----
    wait_vm0();                         // acks this wave's 16B stores
    if (lane == 0) {
      int old = atomicAdd(&pubcnt, 1);  // LDS, CU-coherent, ordered after vmcnt
      if (old == 4 * t + 3)             // 4th wave of step t -> all acks done
        stdword_x(cnt + l * NW + w, t + 1);
    }
  }
}

// ---------------------------------------------------------------------------
// Final projection: out[b][t][v] = h7[b][t][:] . fc_w[v][:] + fc_b[v]
__global__ __launch_bounds__(256) void fc_kernel(
    const _Float16* __restrict__ hseq7,  // [T][32][64][8] fp16
    const float* __restrict__ fcw,       // [23][256]
    const float* __restrict__ fcb,       // [23]
    float* __restrict__ out)             // [64][512][23]
{
  const int t = blockIdx.x;
  const int tid = threadIdx.x;
  __shared__ __align__(16) _Float16 hbuf[32 * 64 * 8];
  __shared__ float wbuf[23 * 256];
  __shared__ float bbuf[24];

  const _Float16* src = hseq7 + (size_t)t * TSTRIDE;
  for (int i = tid; i < 32 * 64; i += 256)
    ((half8*)hbuf)[i] = ((const half8*)src)[i];
  for (int i = tid; i < 23 * 256; i += 256) wbuf[i] = fcw[i];
  if (tid < 23) bbuf[tid] = fcb[tid];
  __syncthreads();

  for (int o = tid; o < 64 * 23; o += 256) {
    int b = o / 23, v = o - b * 23;
    float acc = bbuf[v];
#pragma unroll 4
    for (int kc = 0; kc < 32; ++kc) {
      half8 hv = *(const half8*)(hbuf + ((kc * 64 + b) << 3));
      const float* wr = wbuf + v * 256 + kc * 8;
#pragma unroll
      for (int j = 0; j < 8; ++j) acc += (float)hv[j] * wr[j];
    }
    out[((size_t)b * TT + t) * 23 + v] = acc;
  }
}

// ---------------------------------------------------------------------------
extern "C" void kernel_launch(void* const* d_in, const int* in_sizes, int n_in,
                              void* d_out, int out_size, void* d_ws, size_t ws_size,
                              hipStream_t stream) {
  const int*   x        = (const int*)d_in[0];
  const float* emb      = (const float*)d_in[1];
  const float* Wih0     = (const float*)d_in[2];
  const float* Wih_rest = (const float*)d_in[3];
  const float* Whh      = (const float*)d_in[4];
  const float* bihp     = (const float*)d_in[5];
  const float* bhhp     = (const float*)d_in[6];
  const float* fcw      = (const float*)d_in[7];
  const float* fcb      = (const float*)d_in[8];
  float* out = (float*)d_out;

  char* ws = (char*)d_ws;
  // ws layout (proven): cnt @0 (1KB used) | table @16384 | hseq @131072 (128MB)
  int*      cnt   = (int*)ws;
  float*    table = (float*)(ws + 16384);              // 23*1024*4 = 94208 B
  _Float16* hseq  = (_Float16*)(ws + 131072);          // 8 * 16 MB

  hipMemsetAsync(ws, 0, 16384, stream);  // counters
  build_xg0<<<(23 * G4 + 255) / 256, 256, 0, stream>>>(emb, Wih0, table);
  lstm_pipeline<<<NL * NW, 256, 0, stream>>>(x, Wih_rest, Whh, bihp, bhhp, table, hseq, cnt);
  fc_kernel<<<TT, 256, 0, stream>>>(hseq + (size_t)7 * LSTRIDE, fcw, fcb, out);
}

// Round 10
// 2109.244 us; speedup vs baseline: 1.5257x; 1.5257x over previous
//
#include <hip/hip_runtime.h>
#include <cstdint>
#include <cstddef>

// Problem constants
#define BB   64     // batch
#define TT   512    // time steps
#define HH   256    // hidden
#define G4   1024   // 4*H
#define NL   8      // layers
#define NW   32     // workgroups per layer (hidden-unit slices)
#define HPW  8      // hidden units per WG
#define NR   32     // gate rows per WG (4 gates * HPW)

// Watchdog: poll breaks after this many iterations and proceeds (bounded
// wrong-answer instead of GPU hang). Never triggers when protocol is sound.
#define POLL_BOUND (1 << 15)

typedef _Float16 half8 __attribute__((ext_vector_type(8)));
typedef float   floatx4 __attribute__((ext_vector_type(4)));

__device__ __forceinline__ float sigm(float v)   { return 1.0f / (1.0f + __expf(-v)); }
__device__ __forceinline__ float tanh_f(float v) { return 1.0f - 2.0f / (__expf(2.0f * v) + 1.0f); }

// ---- coherence helpers (ONLY the proven system-scope primitives) ----------
// Producer: data stores sc0sc1 -> s_waitcnt vmcnt(0) -> flag store sc0sc1.
// Consumer: poll flag sc0sc1; then PLAIN cached loads of the data (each data
// address is written exactly once per launch and only read after the flag:
// first-touch L2 fill pulls post-store bytes from IF$). Proven at 1908us
// baseline and R5/R7/R9 passes.
// Session ledger: 2B sc0sc1 publishes -> 2x write amplification (R7);
// serializing every wave's vmcnt(0) ack before the polls -> +1.2-2.4us/step
// (R7/R9); baseline's wave0-publish || waves2/3-poll overlap is essential.
__device__ __forceinline__ void gstore8_x(_Float16* p, half8 d) {
  asm volatile("global_store_dwordx4 %0, %1, off sc0 sc1" :: "v"(p), "v"(d) : "memory");
}
__device__ __forceinline__ void stdword_x(int* p, int v) {
  asm volatile("global_store_dword %0, %1, off sc0 sc1" :: "v"(p), "v"(v) : "memory");
}
__device__ __forceinline__ void wait_vm0() {
  asm volatile("s_waitcnt vmcnt(0)" ::: "memory");
}
__device__ __forceinline__ int ldflag_x(const int* p) {
  int v; asm volatile("global_load_dword %0, %1, off sc0 sc1" : "=v"(v) : "v"(p) : "memory");
  wait_vm0(); return v;
}

// hseq layout per layer: [t][kblk=H/8=32][b=64][8] fp16 (MFMA A-fragment friendly)
#define TSTRIDE ((size_t)32 * BB * 8)         // 16384 elems per t
#define LSTRIDE ((size_t)TT * TSTRIDE)        // 8,388,608 elems per layer (16 MB)

// ---------------------------------------------------------------------------
// xg0 table: table[v][n] = sum_e emb[v][e] * Wih0[n][e]   (biases NOT included)
__global__ void build_xg0(const float* __restrict__ emb, const float* __restrict__ Wih0,
                          float* __restrict__ table) {
  int i = blockIdx.x * 256 + threadIdx.x;
  if (i >= 23 * G4) return;
  int v = i >> 10, n = i & (G4 - 1);
  float a = 0.f;
#pragma unroll
  for (int e = 0; e < 16; ++e) a += emb[v * 16 + e] * Wih0[n * 16 + e];
  table[i] = a;
}

// ---------------------------------------------------------------------------
// Persistent pipelined LSTM -- the PROVEN 1908us baseline structure (8 layers
// x 32 slices x 256 thr, LDS weights, wave0-publish || waves2/3-poll overlap)
// with exactly ONE change: the glds gate roundtrip + barrier B are replaced
// by the shfl_xor(8) in-register gate exchange (verified correct in R7/R9).
// Two barriers per step (was 3). Everything from barrier C onward -- wave0's
// 64x16B publish, solo vmcnt(0), cnt release, waves 1-3 running ahead to the
// next polls -- is byte-identical to the baseline.
__global__ __launch_bounds__(256, 1) void lstm_pipeline(
    const int*   __restrict__ x,         // [B][T]
    const float* __restrict__ Wih_rest,  // [7][1024][256]
    const float* __restrict__ Whh,       // [8][1024][256]
    const float* __restrict__ bih,       // [8][1024]
    const float* __restrict__ bhh,       // [8][1024]
    const float* __restrict__ xg0t,      // [23][1024]
    _Float16* __restrict__ hseq,         // NL * LSTRIDE fp16
    int* __restrict__ cnt)               // [NL][NW] step counters (IF$)
{
  const int l   = blockIdx.x & 7;
  const int w   = blockIdx.x >> 3;
  const int tid = threadIdx.x;
  const int lane = tid & 63;
  const int p    = tid >> 6;        // wave index = M-tile index (batch/16)

  __shared__ __align__(16) _Float16 wlds[64 * NR * 8]; // [kc 0..63][n 0..31][8]
  __shared__ __align__(16) _Float16 hl[BB * 8];        // h staging for publish
  __shared__ float  blds[NR];
  __shared__ float  tlds[23 * NR];

  // ---- one-time init: gather this WG's 32 gate rows into LDS as fp16 ----
  // wlds n-rows: 0..7 = gate i (units 0..7), 8..15 = f, 16..23 = g, 24..31 = o
  for (int idx = tid; idx < 64 * NR; idx += 256) {
    int kc = idx >> 5;          // 0..31 input half, 32..63 recurrent half
    int n  = idx & 31;
    int g = n >> 3, jl = n & 7;
    int gr = g * 256 + w * HPW + jl;
    float v[8];
    if (kc < 32) {
      if (l == 0) { for (int j = 0; j < 8; ++j) v[j] = 0.f; }
      else {
        const float* src = Wih_rest + ((size_t)(l - 1) * G4 + gr) * HH + kc * 8;
        for (int j = 0; j < 8; ++j) v[j] = src[j];
      }
    } else {
      const float* src = Whh + ((size_t)l * G4 + gr) * HH + (kc - 32) * 8;
      for (int j = 0; j < 8; ++j) v[j] = src[j];
    }
    _Float16* dst = wlds + (size_t)idx * 8;
    for (int j = 0; j < 8; ++j) dst[j] = (_Float16)v[j];
  }
  if (tid < NR) {
    int g = tid >> 3, jl = tid & 7;
    int gr = g * 256 + w * HPW + jl;
    blds[tid] = bih[l * G4 + gr] + bhh[l * G4 + gr];
  }
  if (l == 0) {
    for (int idx = tid; idx < 23 * NR; idx += 256) {
      int v = idx >> 5, n = idx & 31;
      int g = n >> 3, jl = n & 7;
      tlds[idx] = xg0t[v * G4 + g * 256 + w * HPW + jl];
    }
  }
  // agent-scope acquire: invalidate stale L1/L2 lines before cached h reads
  if (tid == 0) (void)__hip_atomic_load(cnt, __ATOMIC_ACQUIRE, __HIP_MEMORY_SCOPE_AGENT);
  __syncthreads();

  const int arow = p * 16 + (lane & 15);  // A-fragment batch row
  const int kq   = lane >> 4;             // quarter-wave -> k chunk within tile
  const int n0   = lane & 15;             // B-fragment col (tile 0)
  const int n1   = 16 + n0;               // B-fragment col (tile 1)
  const int cu   = lane & 7;              // cell: unit within slice
  const bool cellane = (n0 < 8);          // lanes that own a unit's cell
  const int rowb = p * 16 + kq * 4;       // cell: first of this lane's 4 batch rows

  const _Float16* hin  = hseq + (size_t)(l > 0 ? l - 1 : 0) * LSTRIDE;
  _Float16*       hrec = hseq + (size_t)l * LSTRIDE;

  float bi = 0.f, bf = 0.f, bg = 0.f, bo = 0.f;
  if (cellane) { bi = blds[cu]; bf = blds[8 + cu]; bg = blds[16 + cu]; bo = blds[24 + cu]; }

  float cst[4] = {0.f, 0.f, 0.f, 0.f};    // c-state: batch rowb+r, unit w*8+cu

  for (int t = 0; t < TT; ++t) {
    // ---- parallel polls: wave3 = own layer step t-1, wave2 = layer below ----
    if (t > 0 && p == 3) {
      const int* f = cnt + l * NW;
      for (int it = 0; it < POLL_BOUND; ++it) {
        int v = ldflag_x(f + (lane & 31));
        if (__all(v >= t)) break;
        __builtin_amdgcn_s_sleep(1);
      }
    }
    if (l > 0 && p == 2) {
      const int* f = cnt + (l - 1) * NW;
      for (int it = 0; it < POLL_BOUND; ++it) {
        int v = ldflag_x(f + (lane & 31));
        if (__all(v >= t + 1)) break;
        __builtin_amdgcn_s_sleep(1);
      }
    }
    __syncthreads();   // barrier A

    // ---- issue ALL loads (input half + recurrent half), plain cached ----
    half8 aA[8], aB[8];
    if (l > 0) {
      const _Float16* ain = hin + (size_t)t * TSTRIDE;
#pragma unroll
      for (int kt = 0; kt < 8; ++kt) {
        int kc = kt * 4 + kq;
        aA[kt] = *(const half8*)(ain + ((size_t)(kc * 64 + arow) << 3));
      }
    }
    if (t > 0) {
      const _Float16* ain = hrec + (size_t)(t - 1) * TSTRIDE;
#pragma unroll
      for (int kt = 0; kt < 8; ++kt) {
        int kc = kt * 4 + kq;
        aB[kt] = *(const half8*)(ain + ((size_t)(kc * 64 + arow) << 3));
      }
    }

    floatx4 acc0 = {0.f, 0.f, 0.f, 0.f};   // tile0: cols = {i x8, f x8}
    floatx4 acc1 = {0.f, 0.f, 0.f, 0.f};   // tile1: cols = {g x8, o x8}
    if (l > 0) {
#pragma unroll
      for (int kt = 0; kt < 8; ++kt) {
        int kc = kt * 4 + kq;
        half8 w0 = *(const half8*)(wlds + ((kc * 32 + n0) << 3));
        half8 w1 = *(const half8*)(wlds + ((kc * 32 + n1) << 3));
        acc0 = __builtin_amdgcn_mfma_f32_16x16x32_f16(aA[kt], w0, acc0, 0, 0, 0);
        acc1 = __builtin_amdgcn_mfma_f32_16x16x32_f16(aA[kt], w1, acc1, 0, 0, 0);
      }
    }
    if (t > 0) {
#pragma unroll
      for (int kt = 0; kt < 8; ++kt) {
        int kc = kt * 4 + kq;
        half8 w0 = *(const half8*)(wlds + (((32 + kc) * 32 + n0) << 3));
        half8 w1 = *(const half8*)(wlds + (((32 + kc) * 32 + n1) << 3));
        acc0 = __builtin_amdgcn_mfma_f32_16x16x32_f16(aB[kt], w0, acc0, 0, 0, 0);
        acc1 = __builtin_amdgcn_mfma_f32_16x16x32_f16(aB[kt], w1, acc1, 0, 0, 0);
      }
    }

    // ---- (J) gate exchange: lane c<8 holds i,g of unit c; partner c+8 holds
    //      f,o of the same unit. Two shfl_xor(8) complete the set. C layout:
    //      col = lane&15, row = kq*4 + r (+ p*16). Verified in R7/R9. ----
    float xf[4], xo[4];
#pragma unroll
    for (int r = 0; r < 4; ++r) {
      xf[r] = __shfl_xor(acc0[r], 8);
      xo[r] = __shfl_xor(acc1[r], 8);
    }

    // ---- cell in-register -> hl staging (2B LDS writes), baseline shape ----
    if (cellane) {
#pragma unroll
      for (int r = 0; r < 4; ++r) {
        float gi = acc0[r] + bi;
        float gf = xf[r]   + bf;
        float gg = acc1[r] + bg;
        float go = xo[r]   + bo;
        if (l == 0) {
          const int xv = x[(rowb + r) * TT + t];
          const float* tb = tlds + xv * NR;
          gi += tb[cu]; gf += tb[8 + cu]; gg += tb[16 + cu]; go += tb[24 + cu];
        }
        const float iv = sigm(gi), fv = sigm(gf), gv = tanh_f(gg), ov = sigm(go);
        cst[r] = fv * cst[r] + iv * gv;
        const float hv = ov * tanh_f(cst[r]);
        hl[(rowb + r) * 8 + cu] = (_Float16)hv;
      }
    }
    __syncthreads();   // barrier C: hl complete

    // ---- publish (BASELINE): wave0 stores the whole 1KB slice contiguously
    //      (64 lanes x 16B = one store instruction), waits on ITS OWN stores
    //      only, then releases. Waves 1-3 run ahead to the next loop-top
    //      polls -- the ack/release overlaps the next step's poll latency. ----
    if (tid < 64) {
      half8 hv = *(const half8*)(hl + tid * 8);
      gstore8_x(hrec + (size_t)t * TSTRIDE + ((size_t)(w * 64 + tid) << 3), hv);
      wait_vm0();      // wave0's h stores are at the coherence point
      if (tid == 0)
        stdword_x(cnt + l * NW + w, t + 1);   // release
    }
    // next iteration's barrier A closes the step
  }
}

// ---------------------------------------------------------------------------
// Final projection: out[b][t][v] = h7[b][t][:] . fc_w[v][:] + fc_b[v]
__global__ __launch_bounds__(256) void fc_kernel(
    const _Float16* __restrict__ hseq7,  // [T][32][64][8] fp16
    const float* __restrict__ fcw,       // [23][256]
    const float* __restrict__ fcb,       // [23]
    float* __restrict__ out)             // [64][512][23]
{
  const int t = blockIdx.x;
  const int tid = threadIdx.x;
  __shared__ __align__(16) _Float16 hbuf[32 * 64 * 8];
  __shared__ float wbuf[23 * 256];
  __shared__ float bbuf[24];

  const _Float16* src = hseq7 + (size_t)t * TSTRIDE;
  for (int i = tid; i < 32 * 64; i += 256)
    ((half8*)hbuf)[i] = ((const half8*)src)[i];
  for (int i = tid; i < 23 * 256; i += 256) wbuf[i] = fcw[i];
  if (tid < 23) bbuf[tid] = fcb[tid];
  __syncthreads();

  for (int o = tid; o < 64 * 23; o += 256) {
    int b = o / 23, v = o - b * 23;
    float acc = bbuf[v];
#pragma unroll 4
    for (int kc = 0; kc < 32; ++kc) {
      half8 hv = *(const half8*)(hbuf + ((kc * 64 + b) << 3));
      const float* wr = wbuf + v * 256 + kc * 8;
#pragma unroll
      for (int j = 0; j < 8; ++j) acc += (float)hv[j] * wr[j];
    }
    out[((size_t)b * TT + t) * 23 + v] = acc;
  }
}

// ---------------------------------------------------------------------------
extern "C" void kernel_launch(void* const* d_in, const int* in_sizes, int n_in,
                              void* d_out, int out_size, void* d_ws, size_t ws_size,
                              hipStream_t stream) {
  const int*   x        = (const int*)d_in[0];
  const float* emb      = (const float*)d_in[1];
  const float* Wih0     = (const float*)d_in[2];
  const float* Wih_rest = (const float*)d_in[3];
  const float* Whh      = (const float*)d_in[4];
  const float* bihp     = (const float*)d_in[5];
  const float* bhhp     = (const float*)d_in[6];
  const float* fcw      = (const float*)d_in[7];
  const float* fcb      = (const float*)d_in[8];
  float* out = (float*)d_out;

  char* ws = (char*)d_ws;
  // ws layout (proven): cnt @0 (1KB used) | table @16384 | hseq @131072 (128MB)
  int*      cnt   = (int*)ws;
  float*    table = (float*)(ws + 16384);              // 23*1024*4 = 94208 B
  _Float16* hseq  = (_Float16*)(ws + 131072);          // 8 * 16 MB

  hipMemsetAsync(ws, 0, 16384, stream);  // counters
  build_xg0<<<(23 * G4 + 255) / 256, 256, 0, stream>>>(emb, Wih0, table);
  lstm_pipeline<<<NL * NW, 256, 0, stream>>>(x, Wih_rest, Whh, bihp, bhhp, table, hseq, cnt);
  fc_kernel<<<TT, 256, 0, stream>>>(hseq + (size_t)7 * LSTRIDE, fcw, fcb, out);
}

// Round 11
// 1867.478 us; speedup vs baseline: 1.7232x; 1.1295x over previous
//
#include <hip/hip_runtime.h>
#include <cstdint>
#include <cstddef>

// Problem constants
#define BB   64     // batch
#define TT   512    // time steps
#define HH   256    // hidden
#define G4   1024   // 4*H
#define NL   8      // layers
#define NW   32     // workgroups per layer (hidden-unit slices)
#define HPW  8      // hidden units per WG
#define NR   32     // gate rows per WG (4 gates * HPW)

// Watchdog: poll breaks after this many iterations and proceeds (bounded
// wrong-answer instead of GPU hang). Never triggers when protocol is sound.
#define POLL_BOUND (1 << 15)

typedef _Float16 half8 __attribute__((ext_vector_type(8)));
typedef float   floatx4 __attribute__((ext_vector_type(4)));

__device__ __forceinline__ float sigm(float v)   { return 1.0f / (1.0f + __expf(-v)); }
__device__ __forceinline__ float tanh_f(float v) { return 1.0f - 2.0f / (__expf(2.0f * v) + 1.0f); }

// ---- coherence helpers (ONLY the proven system-scope primitives) ----------
// Producer: data stores sc0sc1 -> s_waitcnt vmcnt(0) -> flag store sc0sc1.
// Consumer: poll flag sc0sc1; then PLAIN cached loads of the data (each data
// address is written exactly once per launch and only read after the flag:
// first-touch L2 fill pulls post-store bytes from IF$). Proven at 1908us
// baseline and R5/R7/R9/R10 passes.
// Session ledger: 2B sc0sc1 publishes -> 2x write amplification (R7);
// serializing every wave's vmcnt(0) ack before the polls -> +1.2-2.4us/step
// (R7/R9); wave0-publish || other-waves-poll overlap is essential (R9->R10);
// half-idle-lane cell with 4 serial cells/lane costs ~+0.2us/step (R10).
__device__ __forceinline__ void gstore8_x(_Float16* p, half8 d) {
  asm volatile("global_store_dwordx4 %0, %1, off sc0 sc1" :: "v"(p), "v"(d) : "memory");
}
__device__ __forceinline__ void stdword_x(int* p, int v) {
  asm volatile("global_store_dword %0, %1, off sc0 sc1" :: "v"(p), "v"(v) : "memory");
}
__device__ __forceinline__ void wait_vm0() {
  asm volatile("s_waitcnt vmcnt(0)" ::: "memory");
}
__device__ __forceinline__ int ldflag_x(const int* p) {
  int v; asm volatile("global_load_dword %0, %1, off sc0 sc1" : "=v"(v) : "v"(p) : "memory");
  wait_vm0(); return v;
}

// hseq layout per layer: [t][kblk=H/8=32][b=64][8] fp16 (MFMA A-fragment friendly)
#define TSTRIDE ((size_t)32 * BB * 8)         // 16384 elems per t
#define LSTRIDE ((size_t)TT * TSTRIDE)        // 8,388,608 elems per layer (16 MB)

// ---------------------------------------------------------------------------
// xg0 table: table[v][n] = sum_e emb[v][e] * Wih0[n][e]   (biases NOT included)
__global__ void build_xg0(const float* __restrict__ emb, const float* __restrict__ Wih0,
                          float* __restrict__ table) {
  int i = blockIdx.x * 256 + threadIdx.x;
  if (i >= 23 * G4) return;
  int v = i >> 10, n = i & (G4 - 1);
  float a = 0.f;
#pragma unroll
  for (int e = 0; e < 16; ++e) a += emb[v * 16 + e] * Wih0[n * 16 + e];
  table[i] = a;
}

// ---------------------------------------------------------------------------
// Persistent pipelined LSTM -- proven baseline structure (8 layers x 32
// slices x 256 thr, LDS weights, wave0-publish || waves2/3-poll) with:
//  (J2) shfl_xor(8) gate exchange, cell on ALL 64 lanes (lo lanes rows 0,1;
//       hi lanes rows 2,3 -- both halves hold complete i/f/g/o after the
//       exchange). 2 cells/lane = baseline cell cost, no barrier B.
//  (H)  input-half hoist: forward poll targets min(t+2,TT) (one-step
//       lookahead), so at the top of step t the data h^{l-1}(t) is ALREADY
//       confirmed (by step t-1's poll) -> the 8 aA loads + 16 input MFMAs
//       run BEFORE the polls/barrier, hidden under the own-layer flag wait.
//       Post-barrier critical path = recurrent load + 16 MFMA + cell only.
//       Skew becomes 2 steps/layer (fill +~30us, one-time). t==0 does its
//       input half after the first poll (fwd>=2 confirmed covers >=1).
__global__ __launch_bounds__(256, 1) void lstm_pipeline(
    const int*   __restrict__ x,         // [B][T]
    const float* __restrict__ Wih_rest,  // [7][1024][256]
    const float* __restrict__ Whh,       // [8][1024][256]
    const float* __restrict__ bih,       // [8][1024]
    const float* __restrict__ bhh,       // [8][1024]
    const float* __restrict__ xg0t,      // [23][1024]
    _Float16* __restrict__ hseq,         // NL * LSTRIDE fp16
    int* __restrict__ cnt)               // [NL][NW] step counters (IF$)
{
  const int l   = blockIdx.x & 7;
  const int w   = blockIdx.x >> 3;
  const int tid = threadIdx.x;
  const int lane = tid & 63;
  const int p    = tid >> 6;        // wave index = M-tile index (batch/16)

  __shared__ __align__(16) _Float16 wlds[64 * NR * 8]; // [kc 0..63][n 0..31][8]
  __shared__ __align__(16) _Float16 hl[BB * 8];        // h staging for publish
  __shared__ float  blds[NR];
  __shared__ float  tlds[23 * NR];

  // ---- one-time init: gather this WG's 32 gate rows into LDS as fp16 ----
  // wlds n-rows: 0..7 = gate i (units 0..7), 8..15 = f, 16..23 = g, 24..31 = o
  for (int idx = tid; idx < 64 * NR; idx += 256) {
    int kc = idx >> 5;          // 0..31 input half, 32..63 recurrent half
    int n  = idx & 31;
    int g = n >> 3, jl = n & 7;
    int gr = g * 256 + w * HPW + jl;
    float v[8];
    if (kc < 32) {
      if (l == 0) { for (int j = 0; j < 8; ++j) v[j] = 0.f; }
      else {
        const float* src = Wih_rest + ((size_t)(l - 1) * G4 + gr) * HH + kc * 8;
        for (int j = 0; j < 8; ++j) v[j] = src[j];
      }
    } else {
      const float* src = Whh + ((size_t)l * G4 + gr) * HH + (kc - 32) * 8;
      for (int j = 0; j < 8; ++j) v[j] = src[j];
    }
    _Float16* dst = wlds + (size_t)idx * 8;
    for (int j = 0; j < 8; ++j) dst[j] = (_Float16)v[j];
  }
  if (tid < NR) {
    int g = tid >> 3, jl = tid & 7;
    int gr = g * 256 + w * HPW + jl;
    blds[tid] = bih[l * G4 + gr] + bhh[l * G4 + gr];
  }
  if (l == 0) {
    for (int idx = tid; idx < 23 * NR; idx += 256) {
      int v = idx >> 5, n = idx & 31;
      int g = n >> 3, jl = n & 7;
      tlds[idx] = xg0t[v * G4 + g * 256 + w * HPW + jl];
    }
  }
  // agent-scope acquire: invalidate stale L1/L2 lines before cached h reads
  if (tid == 0) (void)__hip_atomic_load(cnt, __ATOMIC_ACQUIRE, __HIP_MEMORY_SCOPE_AGENT);
  __syncthreads();

  const int arow = p * 16 + (lane & 15);  // A-fragment batch row
  const int kq   = lane >> 4;             // quarter-wave -> k chunk within tile
  const int n0   = lane & 15;             // B-fragment col (tile 0)
  const int n1   = 16 + n0;               // B-fragment col (tile 1)
  const int cu   = lane & 7;              // cell: unit within slice
  const bool lowh = (n0 < 8);             // lo half: rows 0,1; hi half: rows 2,3
  const int roff = lowh ? 0 : 2;
  const int rowb = p * 16 + kq * 4;       // first of this quarter's 4 batch rows

  const _Float16* hin  = hseq + (size_t)(l > 0 ? l - 1 : 0) * LSTRIDE;
  _Float16*       hrec = hseq + (size_t)l * LSTRIDE;

  const float bi = blds[cu], bf = blds[8 + cu], bg = blds[16 + cu], bo = blds[24 + cu];

  float cst[2] = {0.f, 0.f};   // c-state: batch rowb+roff+rr, unit w*8+cu

  for (int t = 0; t < TT; ++t) {
    floatx4 acc0 = {0.f, 0.f, 0.f, 0.f};   // tile0: cols = {i x8, f x8}
    floatx4 acc1 = {0.f, 0.f, 0.f, 0.f};   // tile1: cols = {g x8, o x8}

    // ---- (H) hoisted input half (t>0): h^{l-1}(t) was confirmed by the
    //      previous step's lookahead poll -> compute during the flag wait ----
    if (l > 0 && t > 0) {
      const _Float16* ain = hin + (size_t)t * TSTRIDE;
      half8 aA[8];
#pragma unroll
      for (int kt = 0; kt < 8; ++kt) {
        int kc = kt * 4 + kq;
        aA[kt] = *(const half8*)(ain + ((size_t)(kc * 64 + arow) << 3));
      }
#pragma unroll
      for (int kt = 0; kt < 8; ++kt) {
        int kc = kt * 4 + kq;
        half8 w0 = *(const half8*)(wlds + ((kc * 32 + n0) << 3));
        half8 w1 = *(const half8*)(wlds + ((kc * 32 + n1) << 3));
        acc0 = __builtin_amdgcn_mfma_f32_16x16x32_f16(aA[kt], w0, acc0, 0, 0, 0);
        acc1 = __builtin_amdgcn_mfma_f32_16x16x32_f16(aA[kt], w1, acc1, 0, 0, 0);
      }
    }

    // ---- parallel polls: wave3 = own layer step t-1, wave2 = layer below
    //      with one-step lookahead (enables next step's hoist) ----
    if (t > 0 && p == 3) {
      const int* f = cnt + l * NW;
      for (int it = 0; it < POLL_BOUND; ++it) {
        int v = ldflag_x(f + (lane & 31));
        if (__all(v >= t)) break;
        __builtin_amdgcn_s_sleep(1);
      }
    }
    if (l > 0 && p == 2) {
      const int tgt = (t + 2 < TT) ? t + 2 : TT;
      const int* f = cnt + (l - 1) * NW;
      for (int it = 0; it < POLL_BOUND; ++it) {
        int v = ldflag_x(f + (lane & 31));
        if (__all(v >= tgt)) break;
        __builtin_amdgcn_s_sleep(1);
      }
    }
    __syncthreads();   // barrier A

    // ---- t==0 input half (fwd>=2 just confirmed, covers >=1) ----
    if (l > 0 && t == 0) {
      const _Float16* ain = hin;   // t = 0
      half8 aA[8];
#pragma unroll
      for (int kt = 0; kt < 8; ++kt) {
        int kc = kt * 4 + kq;
        aA[kt] = *(const half8*)(ain + ((size_t)(kc * 64 + arow) << 3));
      }
#pragma unroll
      for (int kt = 0; kt < 8; ++kt) {
        int kc = kt * 4 + kq;
        half8 w0 = *(const half8*)(wlds + ((kc * 32 + n0) << 3));
        half8 w1 = *(const half8*)(wlds + ((kc * 32 + n1) << 3));
        acc0 = __builtin_amdgcn_mfma_f32_16x16x32_f16(aA[kt], w0, acc0, 0, 0, 0);
        acc1 = __builtin_amdgcn_mfma_f32_16x16x32_f16(aA[kt], w1, acc1, 0, 0, 0);
      }
    }

    // ---- recurrent half: load h(t-1) (first-touch after flag) + 16 MFMAs ----
    if (t > 0) {
      const _Float16* ain = hrec + (size_t)(t - 1) * TSTRIDE;
      half8 aB[8];
#pragma unroll
      for (int kt = 0; kt < 8; ++kt) {
        int kc = kt * 4 + kq;
        aB[kt] = *(const half8*)(ain + ((size_t)(kc * 64 + arow) << 3));
      }
#pragma unroll
      for (int kt = 0; kt < 8; ++kt) {
        int kc = kt * 4 + kq;
        half8 w0 = *(const half8*)(wlds + (((32 + kc) * 32 + n0) << 3));
        half8 w1 = *(const half8*)(wlds + (((32 + kc) * 32 + n1) << 3));
        acc0 = __builtin_amdgcn_mfma_f32_16x16x32_f16(aB[kt], w0, acc0, 0, 0, 0);
        acc1 = __builtin_amdgcn_mfma_f32_16x16x32_f16(aB[kt], w1, acc1, 0, 0, 0);
      }
    }

    // ---- (J2) packed gate exchange: lanes c<->c+8 swap the two C-rows the
    //      partner needs. After this BOTH halves hold complete i/f/g/o:
    //      lo lane: i,g own (acc0[0..1],acc1[0..1]), f,o received;
    //      hi lane: f,o own (acc0[2..3],acc1[2..3]), i,g received. ----
    const float sa0 = lowh ? acc0[2] : acc0[0];
    const float sa1 = lowh ? acc0[3] : acc0[1];
    const float sb0 = lowh ? acc1[2] : acc1[0];
    const float sb1 = lowh ? acc1[3] : acc1[1];
    const float ra0 = __shfl_xor(sa0, 8);
    const float ra1 = __shfl_xor(sa1, 8);
    const float rb0 = __shfl_xor(sb0, 8);
    const float rb1 = __shfl_xor(sb1, 8);

    // ---- cell on ALL lanes: 2 cells/lane (rows rowb+roff, rowb+roff+1) ----
#pragma unroll
    for (int rr = 0; rr < 2; ++rr) {
      const int r = roff + rr;
      const float own0 = acc0[r], own1 = acc1[r];
      const float oth0 = rr ? ra1 : ra0;
      const float oth1 = rr ? rb1 : rb0;
      float gi = (lowh ? own0 : oth0) + bi;
      float gf = (lowh ? oth0 : own0) + bf;
      float gg = (lowh ? own1 : oth1) + bg;
      float go = (lowh ? oth1 : own1) + bo;
      if (l == 0) {
        const int xv = x[(rowb + r) * TT + t];
        const float* tb = tlds + xv * NR;
        gi += tb[cu]; gf += tb[8 + cu]; gg += tb[16 + cu]; go += tb[24 + cu];
      }
      const float iv = sigm(gi), fv = sigm(gf), gv = tanh_f(gg), ov = sigm(go);
      cst[rr] = fv * cst[rr] + iv * gv;
      const float hv = ov * tanh_f(cst[rr]);
      hl[(rowb + r) * 8 + cu] = (_Float16)hv;
    }
    __syncthreads();   // barrier C: hl complete

    // ---- publish (BASELINE): wave0 stores the whole 1KB slice contiguously,
    //      waits on ITS OWN stores only, then releases. Waves 1-3 run ahead
    //      to the next loop-top hoist + polls. ----
    if (tid < 64) {
      half8 hv = *(const half8*)(hl + tid * 8);
      gstore8_x(hrec + (size_t)t * TSTRIDE + ((size_t)(w * 64 + tid) << 3), hv);
      wait_vm0();      // wave0's h stores are at the coherence point
      if (tid == 0)
        stdword_x(cnt + l * NW + w, t + 1);   // release
    }
    // next iteration's barrier A closes the step
  }
}

// ---------------------------------------------------------------------------
// Final projection: out[b][t][v] = h7[b][t][:] . fc_w[v][:] + fc_b[v]
__global__ __launch_bounds__(256) void fc_kernel(
    const _Float16* __restrict__ hseq7,  // [T][32][64][8] fp16
    const float* __restrict__ fcw,       // [23][256]
    const float* __restrict__ fcb,       // [23]
    float* __restrict__ out)             // [64][512][23]
{
  const int t = blockIdx.x;
  const int tid = threadIdx.x;
  __shared__ __align__(16) _Float16 hbuf[32 * 64 * 8];
  __shared__ float wbuf[23 * 256];
  __shared__ float bbuf[24];

  const _Float16* src = hseq7 + (size_t)t * TSTRIDE;
  for (int i = tid; i < 32 * 64; i += 256)
    ((half8*)hbuf)[i] = ((const half8*)src)[i];
  for (int i = tid; i < 23 * 256; i += 256) wbuf[i] = fcw[i];
  if (tid < 23) bbuf[tid] = fcb[tid];
  __syncthreads();

  for (int o = tid; o < 64 * 23; o += 256) {
    int b = o / 23, v = o - b * 23;
    float acc = bbuf[v];
#pragma unroll 4
    for (int kc = 0; kc < 32; ++kc) {
      half8 hv = *(const half8*)(hbuf + ((kc * 64 + b) << 3));
      const float* wr = wbuf + v * 256 + kc * 8;
#pragma unroll
      for (int j = 0; j < 8; ++j) acc += (float)hv[j] * wr[j];
    }
    out[((size_t)b * TT + t) * 23 + v] = acc;
  }
}

// ---------------------------------------------------------------------------
extern "C" void kernel_launch(void* const* d_in, const int* in_sizes, int n_in,
                              void* d_out, int out_size, void* d_ws, size_t ws_size,
                              hipStream_t stream) {
  const int*   x        = (const int*)d_in[0];
  const float* emb      = (const float*)d_in[1];
  const float* Wih0     = (const float*)d_in[2];
  const float* Wih_rest = (const float*)d_in[3];
  const float* Whh      = (const float*)d_in[4];
  const float* bihp     = (const float*)d_in[5];
  const float* bhhp     = (const float*)d_in[6];
  const float* fcw      = (const float*)d_in[7];
  const float* fcb      = (const float*)d_in[8];
  float* out = (float*)d_out;

  char* ws = (char*)d_ws;
  // ws layout (proven): cnt @0 (1KB used) | table @16384 | hseq @131072 (128MB)
  int*      cnt   = (int*)ws;
  float*    table = (float*)(ws + 16384);              // 23*1024*4 = 94208 B
  _Float16* hseq  = (_Float16*)(ws + 131072);          // 8 * 16 MB

  hipMemsetAsync(ws, 0, 16384, stream);  // counters
  build_xg0<<<(23 * G4 + 255) / 256, 256, 0, stream>>>(emb, Wih0, table);
  lstm_pipeline<<<NL * NW, 256, 0, stream>>>(x, Wih_rest, Whh, bihp, bhhp, table, hseq, cnt);
  fc_kernel<<<TT, 256, 0, stream>>>(hseq + (size_t)7 * LSTRIDE, fcw, fcb, out);
}

// Round 12
// 1601.747 us; speedup vs baseline: 2.0091x; 1.1659x over previous
//
#include <hip/hip_runtime.h>
#include <cstdint>
#include <cstddef>

// Problem constants
#define BB   64     // batch
#define TT   512    // time steps
#define HH   256    // hidden
#define G4   1024   // 4*H
#define NL   8      // layers
#define NW   32     // workgroups per layer (hidden-unit slices)
#define HPW  8      // hidden units per WG
#define NR   32     // gate rows per WG (4 gates * HPW)

// Watchdog: poll breaks after this many iterations and proceeds (bounded
// wrong-answer instead of GPU hang). Never triggers when protocol is sound.
#define POLL_BOUND (1 << 15)

typedef _Float16 half8 __attribute__((ext_vector_type(8)));
typedef float   floatx4 __attribute__((ext_vector_type(4)));

__device__ __forceinline__ float sigm(float v)   { return 1.0f / (1.0f + __expf(-v)); }
__device__ __forceinline__ float tanh_f(float v) { return 1.0f - 2.0f / (__expf(2.0f * v) + 1.0f); }

// ---- coherence helpers (ONLY the proven system-scope primitives) ----------
// Producer: data stores sc0sc1 -> s_waitcnt vmcnt(0) -> flag store sc0sc1.
// Consumer: poll flag sc0sc1; then PLAIN cached loads of the data (each data
// address is written exactly once per launch and only read after the flag:
// first-touch L2 fill pulls post-store bytes from IF$). Proven at 1908us
// baseline and R5/R7/R9/R10/R11 passes.
// Session ledger: 2B sc0sc1 publishes -> 2x write amplification (R7);
// serializing every wave's vmcnt(0) ack before the polls -> +1.2-2.4us/step
// (R7/R9); wave0-publish || other-waves-poll overlap is essential (R9->R10);
// input-half hoist into the flag-wait window + all-lane cell = -240us (R11).
__device__ __forceinline__ void gstore8_x(_Float16* p, half8 d) {
  asm volatile("global_store_dwordx4 %0, %1, off sc0 sc1" :: "v"(p), "v"(d) : "memory");
}
__device__ __forceinline__ void stdword_x(int* p, int v) {
  asm volatile("global_store_dword %0, %1, off sc0 sc1" :: "v"(p), "v"(v) : "memory");
}
__device__ __forceinline__ void wait_vm0() {
  asm volatile("s_waitcnt vmcnt(0)" ::: "memory");
}
__device__ __forceinline__ int ldflag_x(const int* p) {
  int v; asm volatile("global_load_dword %0, %1, off sc0 sc1" : "=v"(v) : "v"(p) : "memory");
  wait_vm0(); return v;
}

// hseq layout per layer: [t][kblk=H/8=32][b=64][8] fp16 (MFMA A-fragment friendly)
#define TSTRIDE ((size_t)32 * BB * 8)         // 16384 elems per t
#define LSTRIDE ((size_t)TT * TSTRIDE)        // 8,388,608 elems per layer (16 MB)

// ---------------------------------------------------------------------------
// xg0 table: table[v][n] = sum_e emb[v][e] * Wih0[n][e]   (biases NOT included)
__global__ void build_xg0(const float* __restrict__ emb, const float* __restrict__ Wih0,
                          float* __restrict__ table) {
  int i = blockIdx.x * 256 + threadIdx.x;
  if (i >= 23 * G4) return;
  int v = i >> 10, n = i & (G4 - 1);
  float a = 0.f;
#pragma unroll
  for (int e = 0; e < 16; ++e) a += emb[v * 16 + e] * Wih0[n * 16 + e];
  table[i] = a;
}

// ---------------------------------------------------------------------------
// Persistent pipelined LSTM -- proven R11 structure (8 layers x 32 slices x
// 256 thr, LDS weights, wave0-publish || waves2/3-poll, input-half hoist,
// all-lane cell) + s_setprio(1) around wave0's publish/ack/release (the
// cross-WG critical edge competes with polling waves for memory issue).
__global__ __launch_bounds__(256, 1) void lstm_pipeline(
    const int*   __restrict__ x,         // [B][T]
    const float* __restrict__ Wih_rest,  // [7][1024][256]
    const float* __restrict__ Whh,       // [8][1024][256]
    const float* __restrict__ bih,       // [8][1024]
    const float* __restrict__ bhh,       // [8][1024]
    const float* __restrict__ xg0t,      // [23][1024]
    _Float16* __restrict__ hseq,         // NL * LSTRIDE fp16
    int* __restrict__ cnt)               // [NL][NW] step counters (IF$)
{
  const int l   = blockIdx.x & 7;
  const int w   = blockIdx.x >> 3;
  const int tid = threadIdx.x;
  const int lane = tid & 63;
  const int p    = tid >> 6;        // wave index = M-tile index (batch/16)

  __shared__ __align__(16) _Float16 wlds[64 * NR * 8]; // [kc 0..63][n 0..31][8]
  __shared__ __align__(16) _Float16 hl[BB * 8];        // h staging for publish
  __shared__ float  blds[NR];
  __shared__ float  tlds[23 * NR];

  // ---- one-time init: gather this WG's 32 gate rows into LDS as fp16 ----
  // wlds n-rows: 0..7 = gate i (units 0..7), 8..15 = f, 16..23 = g, 24..31 = o
  for (int idx = tid; idx < 64 * NR; idx += 256) {
    int kc = idx >> 5;          // 0..31 input half, 32..63 recurrent half
    int n  = idx & 31;
    int g = n >> 3, jl = n & 7;
    int gr = g * 256 + w * HPW + jl;
    float v[8];
    if (kc < 32) {
      if (l == 0) { for (int j = 0; j < 8; ++j) v[j] = 0.f; }
      else {
        const float* src = Wih_rest + ((size_t)(l - 1) * G4 + gr) * HH + kc * 8;
        for (int j = 0; j < 8; ++j) v[j] = src[j];
      }
    } else {
      const float* src = Whh + ((size_t)l * G4 + gr) * HH + (kc - 32) * 8;
      for (int j = 0; j < 8; ++j) v[j] = src[j];
    }
    _Float16* dst = wlds + (size_t)idx * 8;
    for (int j = 0; j < 8; ++j) dst[j] = (_Float16)v[j];
  }
  if (tid < NR) {
    int g = tid >> 3, jl = tid & 7;
    int gr = g * 256 + w * HPW + jl;
    blds[tid] = bih[l * G4 + gr] + bhh[l * G4 + gr];
  }
  if (l == 0) {
    for (int idx = tid; idx < 23 * NR; idx += 256) {
      int v = idx >> 5, n = idx & 31;
      int g = n >> 3, jl = n & 7;
      tlds[idx] = xg0t[v * G4 + g * 256 + w * HPW + jl];
    }
  }
  // agent-scope acquire: invalidate stale L1/L2 lines before cached h reads
  if (tid == 0) (void)__hip_atomic_load(cnt, __ATOMIC_ACQUIRE, __HIP_MEMORY_SCOPE_AGENT);
  __syncthreads();

  const int arow = p * 16 + (lane & 15);  // A-fragment batch row
  const int kq   = lane >> 4;             // quarter-wave -> k chunk within tile
  const int n0   = lane & 15;             // B-fragment col (tile 0)
  const int n1   = 16 + n0;               // B-fragment col (tile 1)
  const int cu   = lane & 7;              // cell: unit within slice
  const bool lowh = (n0 < 8);             // lo half: rows 0,1; hi half: rows 2,3
  const int roff = lowh ? 0 : 2;
  const int rowb = p * 16 + kq * 4;       // first of this quarter's 4 batch rows

  const _Float16* hin  = hseq + (size_t)(l > 0 ? l - 1 : 0) * LSTRIDE;
  _Float16*       hrec = hseq + (size_t)l * LSTRIDE;

  const float bi = blds[cu], bf = blds[8 + cu], bg = blds[16 + cu], bo = blds[24 + cu];

  float cst[2] = {0.f, 0.f};   // c-state: batch rowb+roff+rr, unit w*8+cu

  for (int t = 0; t < TT; ++t) {
    floatx4 acc0 = {0.f, 0.f, 0.f, 0.f};   // tile0: cols = {i x8, f x8}
    floatx4 acc1 = {0.f, 0.f, 0.f, 0.f};   // tile1: cols = {g x8, o x8}

    // ---- (H) hoisted input half (t>0): h^{l-1}(t) was confirmed by the
    //      previous step's lookahead poll -> compute during the flag wait ----
    if (l > 0 && t > 0) {
      const _Float16* ain = hin + (size_t)t * TSTRIDE;
      half8 aA[8];
#pragma unroll
      for (int kt = 0; kt < 8; ++kt) {
        int kc = kt * 4 + kq;
        aA[kt] = *(const half8*)(ain + ((size_t)(kc * 64 + arow) << 3));
      }
#pragma unroll
      for (int kt = 0; kt < 8; ++kt) {
        int kc = kt * 4 + kq;
        half8 w0 = *(const half8*)(wlds + ((kc * 32 + n0) << 3));
        half8 w1 = *(const half8*)(wlds + ((kc * 32 + n1) << 3));
        acc0 = __builtin_amdgcn_mfma_f32_16x16x32_f16(aA[kt], w0, acc0, 0, 0, 0);
        acc1 = __builtin_amdgcn_mfma_f32_16x16x32_f16(aA[kt], w1, acc1, 0, 0, 0);
      }
    }

    // ---- parallel polls: wave3 = own layer step t-1, wave2 = layer below
    //      with one-step lookahead (enables next step's hoist) ----
    if (t > 0 && p == 3) {
      const int* f = cnt + l * NW;
      for (int it = 0; it < POLL_BOUND; ++it) {
        int v = ldflag_x(f + (lane & 31));
        if (__all(v >= t)) break;
        __builtin_amdgcn_s_sleep(1);
      }
    }
    if (l > 0 && p == 2) {
      const int tgt = (t + 2 < TT) ? t + 2 : TT;
      const int* f = cnt + (l - 1) * NW;
      for (int it = 0; it < POLL_BOUND; ++it) {
        int v = ldflag_x(f + (lane & 31));
        if (__all(v >= tgt)) break;
        __builtin_amdgcn_s_sleep(1);
      }
    }
    __syncthreads();   // barrier A

    // ---- t==0 input half (fwd>=2 just confirmed, covers >=1) ----
    if (l > 0 && t == 0) {
      const _Float16* ain = hin;   // t = 0
      half8 aA[8];
#pragma unroll
      for (int kt = 0; kt < 8; ++kt) {
        int kc = kt * 4 + kq;
        aA[kt] = *(const half8*)(ain + ((size_t)(kc * 64 + arow) << 3));
      }
#pragma unroll
      for (int kt = 0; kt < 8; ++kt) {
        int kc = kt * 4 + kq;
        half8 w0 = *(const half8*)(wlds + ((kc * 32 + n0) << 3));
        half8 w1 = *(const half8*)(wlds + ((kc * 32 + n1) << 3));
        acc0 = __builtin_amdgcn_mfma_f32_16x16x32_f16(aA[kt], w0, acc0, 0, 0, 0);
        acc1 = __builtin_amdgcn_mfma_f32_16x16x32_f16(aA[kt], w1, acc1, 0, 0, 0);
      }
    }

    // ---- recurrent half: load h(t-1) (first-touch after flag) + 16 MFMAs ----
    if (t > 0) {
      const _Float16* ain = hrec + (size_t)(t - 1) * TSTRIDE;
      half8 aB[8];
#pragma unroll
      for (int kt = 0; kt < 8; ++kt) {
        int kc = kt * 4 + kq;
        aB[kt] = *(const half8*)(ain + ((size_t)(kc * 64 + arow) << 3));
      }
#pragma unroll
      for (int kt = 0; kt < 8; ++kt) {
        int kc = kt * 4 + kq;
        half8 w0 = *(const half8*)(wlds + (((32 + kc) * 32 + n0) << 3));
        half8 w1 = *(const half8*)(wlds + (((32 + kc) * 32 + n1) << 3));
        acc0 = __builtin_amdgcn_mfma_f32_16x16x32_f16(aB[kt], w0, acc0, 0, 0, 0);
        acc1 = __builtin_amdgcn_mfma_f32_16x16x32_f16(aB[kt], w1, acc1, 0, 0, 0);
      }
    }

    // ---- (J2) packed gate exchange: lanes c<->c+8 swap the two C-rows the
    //      partner needs. After this BOTH halves hold complete i/f/g/o. ----
    const float sa0 = lowh ? acc0[2] : acc0[0];
    const float sa1 = lowh ? acc0[3] : acc0[1];
    const float sb0 = lowh ? acc1[2] : acc1[0];
    const float sb1 = lowh ? acc1[3] : acc1[1];
    const float ra0 = __shfl_xor(sa0, 8);
    const float ra1 = __shfl_xor(sa1, 8);
    const float rb0 = __shfl_xor(sb0, 8);
    const float rb1 = __shfl_xor(sb1, 8);

    // ---- cell on ALL lanes: 2 cells/lane (rows rowb+roff, rowb+roff+1) ----
#pragma unroll
    for (int rr = 0; rr < 2; ++rr) {
      const int r = roff + rr;
      const float own0 = acc0[r], own1 = acc1[r];
      const float oth0 = rr ? ra1 : ra0;
      const float oth1 = rr ? rb1 : rb0;
      float gi = (lowh ? own0 : oth0) + bi;
      float gf = (lowh ? oth0 : own0) + bf;
      float gg = (lowh ? own1 : oth1) + bg;
      float go = (lowh ? oth1 : own1) + bo;
      if (l == 0) {
        const int xv = x[(rowb + r) * TT + t];
        const float* tb = tlds + xv * NR;
        gi += tb[cu]; gf += tb[8 + cu]; gg += tb[16 + cu]; go += tb[24 + cu];
      }
      const float iv = sigm(gi), fv = sigm(gf), gv = tanh_f(gg), ov = sigm(go);
      cst[rr] = fv * cst[rr] + iv * gv;
      const float hv = ov * tanh_f(cst[rr]);
      hl[(rowb + r) * 8 + cu] = (_Float16)hv;
    }
    __syncthreads();   // barrier C: hl complete

    // ---- publish: wave0 stores the 1KB slice, acks its own stores, then
    //      releases -- at raised priority so polling waves don't starve the
    //      cross-WG critical edge (T5). Waves 1-3 run ahead to next hoist. ----
    if (tid < 64) {
      __builtin_amdgcn_s_setprio(1);
      half8 hv = *(const half8*)(hl + tid * 8);
      gstore8_x(hrec + (size_t)t * TSTRIDE + ((size_t)(w * 64 + tid) << 3), hv);
      wait_vm0();      // wave0's h stores are at the coherence point
      if (tid == 0)
        stdword_x(cnt + l * NW + w, t + 1);   // release
      __builtin_amdgcn_s_setprio(0);
    }
    // next iteration's barrier A closes the step
  }
}

// ---------------------------------------------------------------------------
// Final projection via MFMA: out[b][t][v] = h7[b][t][:] . fc_w[v][:] + fc_b[v]
// h7 is stored in the exact A-fragment layout [kc][b][8]. N = 23 padded to 32
// (2 tiles). Split-precision weights: w = w_hi + w_lo * 2^-11, both fp16
// (w_lo pre-scaled by 2^11 to stay in normal range); two accumulator sets
// keep the quantization error ~2^-22 relative -- no threshold risk.
__global__ __launch_bounds__(256) void fc_kernel(
    const _Float16* __restrict__ hseq7,  // [T][32][64][8] fp16
    const float* __restrict__ fcw,       // [23][256]
    const float* __restrict__ fcb,       // [23]
    float* __restrict__ out)             // [64][512][23]
{
  const int t = blockIdx.x;
  const int tid = threadIdx.x;
  const int lane = tid & 63;
  const int p = tid >> 6;

  __shared__ __align__(16) _Float16 whi[32 * 32 * 8];  // [kc][n][8] 16KB
  __shared__ __align__(16) _Float16 wlo[32 * 32 * 8];  // residual * 2^11
  __shared__ float bbuf[32];

  for (int idx = tid; idx < 32 * 32; idx += 256) {
    int kc = idx >> 5, n = idx & 31;
    _Float16* dh = whi + (size_t)idx * 8;
    _Float16* dl = wlo + (size_t)idx * 8;
    if (n < 23) {
      const float* src = fcw + n * 256 + kc * 8;
      for (int j = 0; j < 8; ++j) {
        float v = src[j];
        _Float16 hi = (_Float16)v;
        dh[j] = hi;
        dl[j] = (_Float16)((v - (float)hi) * 2048.0f);
      }
    } else {
      for (int j = 0; j < 8; ++j) { dh[j] = (_Float16)0.f; dl[j] = (_Float16)0.f; }
    }
  }
  if (tid < 32) bbuf[tid] = (tid < 23) ? fcb[tid] : 0.f;
  __syncthreads();

  const int arow = p * 16 + (lane & 15);
  const int kq   = lane >> 4;
  const int n0   = lane & 15;
  const int n1   = 16 + n0;

  const _Float16* src = hseq7 + (size_t)t * TSTRIDE;
  floatx4 a0h = {0.f,0.f,0.f,0.f}, a1h = {0.f,0.f,0.f,0.f};
  floatx4 a0l = {0.f,0.f,0.f,0.f}, a1l = {0.f,0.f,0.f,0.f};
#pragma unroll
  for (int kt = 0; kt < 8; ++kt) {
    int kc = kt * 4 + kq;
    half8 a  = *(const half8*)(src + ((size_t)(kc * 64 + arow) << 3));
    half8 h0 = *(const half8*)(whi + ((kc * 32 + n0) << 3));
    half8 h1 = *(const half8*)(whi + ((kc * 32 + n1) << 3));
    half8 l0 = *(const half8*)(wlo + ((kc * 32 + n0) << 3));
    half8 l1 = *(const half8*)(wlo + ((kc * 32 + n1) << 3));
    a0h = __builtin_amdgcn_mfma_f32_16x16x32_f16(a, h0, a0h, 0, 0, 0);
    a1h = __builtin_amdgcn_mfma_f32_16x16x32_f16(a, h1, a1h, 0, 0, 0);
    a0l = __builtin_amdgcn_mfma_f32_16x16x32_f16(a, l0, a0l, 0, 0, 0);
    a1l = __builtin_amdgcn_mfma_f32_16x16x32_f16(a, l1, a1l, 0, 0, 0);
  }

  // C layout: col = lane&15 (vocab), row = kq*4 + r (+p*16) (batch)
  const float rs = 1.0f / 2048.0f;
#pragma unroll
  for (int r = 0; r < 4; ++r) {
    int b = p * 16 + kq * 4 + r;
    out[((size_t)b * TT + t) * 23 + n0] = a0h[r] + a0l[r] * rs + bbuf[n0];
    if (n1 < 23)
      out[((size_t)b * TT + t) * 23 + n1] = a1h[r] + a1l[r] * rs + bbuf[n1];
  }
}

// ---------------------------------------------------------------------------
extern "C" void kernel_launch(void* const* d_in, const int* in_sizes, int n_in,
                              void* d_out, int out_size, void* d_ws, size_t ws_size,
                              hipStream_t stream) {
  const int*   x        = (const int*)d_in[0];
  const float* emb      = (const float*)d_in[1];
  const float* Wih0     = (const float*)d_in[2];
  const float* Wih_rest = (const float*)d_in[3];
  const float* Whh      = (const float*)d_in[4];
  const float* bihp     = (const float*)d_in[5];
  const float* bhhp     = (const float*)d_in[6];
  const float* fcw      = (const float*)d_in[7];
  const float* fcb      = (const float*)d_in[8];
  float* out = (float*)d_out;

  char* ws = (char*)d_ws;
  // ws layout (proven): cnt @0 (1KB used) | table @16384 | hseq @131072 (128MB)
  int*      cnt   = (int*)ws;
  float*    table = (float*)(ws + 16384);              // 23*1024*4 = 94208 B
  _Float16* hseq  = (_Float16*)(ws + 131072);          // 8 * 16 MB

  hipMemsetAsync(ws, 0, 16384, stream);  // counters
  build_xg0<<<(23 * G4 + 255) / 256, 256, 0, stream>>>(emb, Wih0, table);
  lstm_pipeline<<<NL * NW, 256, 0, stream>>>(x, Wih_rest, Whh, bihp, bhhp, table, hseq, cnt);
  fc_kernel<<<TT, 256, 0, stream>>>(hseq + (size_t)7 * LSTRIDE, fcw, fcb, out);
}